// Round 1
// baseline (5171.863 us; speedup 1.0000x reference)
//
#include <hip/hip_runtime.h>
#include <hip/hip_bf16.h>
#include <stdint.h>

#define VOCAB 32000
#define HIDDEN 512
#define TSEQ 1024
#define NWG 8

typedef __attribute__((ext_vector_type(4))) float f32x4;
typedef __attribute__((ext_vector_type(8))) short short8;

// ---------------- kernel: f32 -> bf16 convert (Why_w) ----------------
__global__ __launch_bounds__(256) void k_convert(const float* __restrict__ in,
                                                 __hip_bfloat16* __restrict__ out,
                                                 int n4) {
  int stride = gridDim.x * blockDim.x;
  for (int i = blockIdx.x * blockDim.x + threadIdx.x; i < n4; i += stride) {
    const float4 v = *reinterpret_cast<const float4*>(in + (size_t)i * 4);
    union { __hip_bfloat16 h[4]; ushort4 u; } p;
    p.h[0] = __float2bfloat16(v.x);
    p.h[1] = __float2bfloat16(v.y);
    p.h[2] = __float2bfloat16(v.z);
    p.h[3] = __float2bfloat16(v.w);
    *reinterpret_cast<ushort4*>(out + (size_t)i * 4) = p.u;
  }
}

// ---------------- kernel: pre[t][j] = Wxh_w[j][idx[t]] + Wxh_b[j] + Whh_b[j] ----------------
__global__ __launch_bounds__(512) void k_pre(const int* __restrict__ idx,
                                             const float* __restrict__ h0,
                                             const float* __restrict__ Wxh_w,
                                             const float* __restrict__ Wxh_b,
                                             const float* __restrict__ Whh_b,
                                             float* __restrict__ pre,
                                             float* __restrict__ h_hist) {
  const int t = blockIdx.x;
  const int j = threadIdx.x;
  const int c = idx[t];
  pre[(size_t)t * HIDDEN + j] = Wxh_w[(size_t)j * VOCAB + c] + Wxh_b[j] + Whh_b[j];
  if (t == 0) h_hist[j] = h0[j];  // h_hist[0] = initial hidden state
}

// ---------------- kernel: the sequential scan ----------------
// 8 WGs x 512 threads. WG g owns rows [64g, 64g+64). Weights live in VGPRs:
// thread (r = tid>>3, s = tid&7) holds Whh[64g+r][64s .. 64s+64) in 16 float4s.
// Per step: poll 8 per-step flags (agent-scope acquire), load full h_prev from
// global, 64 FMAs, 3-level shfl_xor reduce over the 8 k-chunk lanes, tanh,
// store slice, __syncthreads, agent-scope release flag store.
__global__ __launch_bounds__(512) void k_scan(const float* __restrict__ pre,
                                              const float* __restrict__ Whh,
                                              float* __restrict__ h_hist,
                                              __hip_bfloat16* __restrict__ h_bf,
                                              unsigned* __restrict__ flags,
                                              float* __restrict__ h_final) {
  const int g = blockIdx.x;
  const int tid = threadIdx.x;
  const int r = tid >> 3;      // 0..63
  const int s = tid & 7;       // 0..7
  const int R = g * 64 + r;    // global row

  float4 w[16];
  const float4* wp = reinterpret_cast<const float4*>(Whh + (size_t)R * HIDDEN + s * 64);
#pragma unroll
  for (int i = 0; i < 16; ++i) w[i] = wp[i];

  for (int t = 1; t <= TSEQ; ++t) {
    // prefetch the additive term early (no dependence on h_prev)
    const float pv = pre[(size_t)(t - 1) * HIDDEN + R];

    if (t > 1) {
      if (tid < NWG) {
        while (__hip_atomic_load(&flags[(size_t)(t - 1) * NWG + tid],
                                 __ATOMIC_ACQUIRE, __HIP_MEMORY_SCOPE_AGENT) == 0) {}
      }
      __syncthreads();
    }

    const float4* hp =
        reinterpret_cast<const float4*>(h_hist + (size_t)(t - 1) * HIDDEN + s * 64);
    float acc = 0.f;
#pragma unroll
    for (int i = 0; i < 16; ++i) {
      const float4 hv = hp[i];
      acc += w[i].x * hv.x;
      acc += w[i].y * hv.y;
      acc += w[i].z * hv.z;
      acc += w[i].w * hv.w;
    }
    // reduce across the 8 lanes (s = 0..7) of this row; groups are 8-aligned in-wave
    acc += __shfl_xor(acc, 1);
    acc += __shfl_xor(acc, 2);
    acc += __shfl_xor(acc, 4);

    if (s == 0) {
      const float y = tanhf(pv + acc);
      h_hist[(size_t)t * HIDDEN + R] = y;
      h_bf[(size_t)(t - 1) * HIDDEN + R] = __float2bfloat16(y);
      if (t == TSEQ) h_final[R] = y;
    }
    __syncthreads();  // all slice stores done (also orders own-WG stores for next step)
    if (tid == 0) {
      __hip_atomic_store(&flags[(size_t)t * NWG + g], 1u,
                         __ATOMIC_RELEASE, __HIP_MEMORY_SCOPE_AGENT);
    }
  }
}

// ---------------- kernel: logits = h_seq @ Why_w^T + bias (bf16 MFMA) ----------------
// A: [TSEQ][HIDDEN] bf16 (h_seq), B: [VOCAB][HIDDEN] bf16 (Why_w), both K-contiguous.
// 128x128 tile, 4 waves in 2x2 of 64x64, 16x16x32 bf16 MFMA, BK=32.
__global__ __launch_bounds__(256) void k_gemm(const __hip_bfloat16* __restrict__ A,
                                              const __hip_bfloat16* __restrict__ B,
                                              const float* __restrict__ bias,
                                              float* __restrict__ C) {
  __shared__ __hip_bfloat16 As[128][32];
  __shared__ __hip_bfloat16 Bs[128][32];
  const int bn = blockIdx.x;  // 0..249
  const int bm = blockIdx.y;  // 0..7
  const int tid = threadIdx.x;
  const int lane = tid & 63;
  const int wid = tid >> 6;
  const int wr = (wid >> 1) * 64;
  const int wc = (wid & 1) * 64;
  const int l15 = lane & 15;
  const int kc = lane >> 4;

  const int sr = tid >> 1;        // staging row 0..127
  const int sc = (tid & 1) * 16;  // staging k offset {0,16}

  const __hip_bfloat16* Ag = A + (size_t)(bm * 128 + sr) * HIDDEN + sc;
  const __hip_bfloat16* Bg = B + (size_t)(bn * 128 + sr) * HIDDEN + sc;

  f32x4 acc[4][4];
#pragma unroll
  for (int m = 0; m < 4; ++m)
#pragma unroll
    for (int n = 0; n < 4; ++n) {
      acc[m][n][0] = 0.f; acc[m][n][1] = 0.f; acc[m][n][2] = 0.f; acc[m][n][3] = 0.f;
    }

  for (int ks = 0; ks < HIDDEN; ks += 32) {
    __syncthreads();  // WAR: previous iteration's reads done
    *reinterpret_cast<short8*>(&As[sr][sc])     = *reinterpret_cast<const short8*>(Ag + ks);
    *reinterpret_cast<short8*>(&As[sr][sc + 8]) = *reinterpret_cast<const short8*>(Ag + ks + 8);
    *reinterpret_cast<short8*>(&Bs[sr][sc])     = *reinterpret_cast<const short8*>(Bg + ks);
    *reinterpret_cast<short8*>(&Bs[sr][sc + 8]) = *reinterpret_cast<const short8*>(Bg + ks + 8);
    __syncthreads();

    short8 af[4], bfr[4];
#pragma unroll
    for (int m = 0; m < 4; ++m)
      af[m] = *reinterpret_cast<const short8*>(&As[wr + m * 16 + l15][kc * 8]);
#pragma unroll
    for (int n = 0; n < 4; ++n)
      bfr[n] = *reinterpret_cast<const short8*>(&Bs[wc + n * 16 + l15][kc * 8]);
#pragma unroll
    for (int m = 0; m < 4; ++m)
#pragma unroll
      for (int n = 0; n < 4; ++n)
        acc[m][n] = __builtin_amdgcn_mfma_f32_16x16x32_bf16(af[m], bfr[n], acc[m][n], 0, 0, 0);
  }

  // epilogue: C/D layout col = lane&15, row = (lane>>4)*4 + q
#pragma unroll
  for (int m = 0; m < 4; ++m) {
#pragma unroll
    for (int n = 0; n < 4; ++n) {
      const int vcol = bn * 128 + wc + n * 16 + l15;
      const float bv = bias[vcol];
#pragma unroll
      for (int q = 0; q < 4; ++q) {
        const int trow = bm * 128 + wr + m * 16 + kc * 4 + q;
        C[(size_t)trow * VOCAB + vcol] = acc[m][n][q] + bv;
      }
    }
  }
}

extern "C" void kernel_launch(void* const* d_in, const int* in_sizes, int n_in,
                              void* d_out, int out_size, void* d_ws, size_t ws_size,
                              hipStream_t stream) {
  (void)in_sizes; (void)n_in; (void)out_size; (void)ws_size;

  const int*   idx   = (const int*)d_in[0];
  const float* h0    = (const float*)d_in[1];
  const float* Wxh_w = (const float*)d_in[2];
  const float* Wxh_b = (const float*)d_in[3];
  const float* Whh_w = (const float*)d_in[4];
  const float* Whh_b = (const float*)d_in[5];
  const float* Why_w = (const float*)d_in[6];
  const float* Why_b = (const float*)d_in[7];
  float* out = (float*)d_out;

  // workspace layout (bytes)
  char* ws = (char*)d_ws;
  __hip_bfloat16* why_bf = (__hip_bfloat16*)(ws);                       // 32,768,000
  float* pre    = (float*)(ws + 32768000);                              // 2,097,152
  float* h_hist = (float*)(ws + 32768000 + 2097152);                    // 2,099,200 (1025 rows)
  __hip_bfloat16* h_bf = (__hip_bfloat16*)(ws + 32768000 + 2097152 + 2099200); // 1,048,576
  unsigned* flags = (unsigned*)(ws + 32768000 + 2097152 + 2099200 + 1048576);  // 32,800

  // flags must be zeroed every call (ws is not re-poisoned between replays)
  hipMemsetAsync(flags, 0, (size_t)(TSEQ + 1) * NWG * sizeof(unsigned), stream);

  k_convert<<<2048, 256, 0, stream>>>(Why_w, why_bf, (VOCAB * HIDDEN) / 4);
  k_pre<<<TSEQ, HIDDEN, 0, stream>>>(idx, h0, Wxh_w, Wxh_b, Whh_b, pre, h_hist);
  k_scan<<<NWG, 512, 0, stream>>>(pre, Whh_w, h_hist, h_bf, flags, out + 32768000);
  k_gemm<<<dim3(VOCAB / 128, TSEQ / 128), 256, 0, stream>>>(h_bf, why_bf, Why_b, out);
}